// Round 8
// baseline (698.483 us; speedup 1.0000x reference)
//
#include <hip/hip_runtime.h>
#include <hip/hip_bf16.h>
#include <stdint.h>

#define N_ROWS 8192
#define DIM    768
#define BM     256
#define BN     256
#define BK     32
#define KTILES (DIM / BK)      // 24
#define NT2    (N_ROWS / BN)   // 32
#define LDS_BYTES 65536

typedef __attribute__((ext_vector_type(8))) short bf16x8;
typedef __attribute__((ext_vector_type(4))) float f32x4;

__device__ __forceinline__ unsigned short f2bf(float f) {
    union { float f; uint32_t i; } v; v.f = f;
    uint32_t u = v.i;
    return (unsigned short)((u + 0x7FFFu + ((u >> 16) & 1u)) >> 16);
}
__device__ __forceinline__ float tstudent(float c) {
    // (1 + 0.5*(1-c))^{-1.5} = t^{-1.5}, t = 1.5 - 0.5c
    float t = 1.5f - 0.5f * c;
    float r = rsqrtf(t);
    return r * r * r;
}

// ---------------- kernel 1: row L2-normalize fp32 -> bf16, fused fp32 diag numerator ----------------
__global__ __launch_bounds__(256) void norm_kernel(const float* __restrict__ z1,
                                                   const float* __restrict__ z2,
                                                   unsigned short* __restrict__ n1,
                                                   unsigned short* __restrict__ n2,
                                                   float* __restrict__ num) {
    int row = blockIdx.x;
    int t = threadIdx.x;
    const float* s1 = z1 + (size_t)row * DIM;
    const float* s2 = z2 + (size_t)row * DIM;
    float a0 = s1[t], a1 = s1[t + 256], a2 = s1[t + 512];
    float b0 = s2[t], b1 = s2[t + 256], b2 = s2[t + 512];
    float ss1 = a0 * a0 + a1 * a1 + a2 * a2;
    float ss2 = b0 * b0 + b1 * b1 + b2 * b2;
    float sd  = a0 * b0 + a1 * b1 + a2 * b2;
    for (int off = 32; off; off >>= 1) {
        ss1 += __shfl_down(ss1, off);
        ss2 += __shfl_down(ss2, off);
        sd  += __shfl_down(sd, off);
    }
    __shared__ float w1[4], w2[4], wd[4];
    __shared__ float sc1_s, sc2_s;
    if ((t & 63) == 0) { int wi = t >> 6; w1[wi] = ss1; w2[wi] = ss2; wd[wi] = sd; }
    __syncthreads();
    if (t == 0) {
        float nrm1 = fmaxf(sqrtf(w1[0] + w1[1] + w1[2] + w1[3]), 1e-8f);
        float nrm2 = fmaxf(sqrtf(w2[0] + w2[1] + w2[2] + w2[3]), 1e-8f);
        float dot  = wd[0] + wd[1] + wd[2] + wd[3];
        sc1_s = 1.0f / nrm1;
        sc2_s = 1.0f / nrm2;
        num[row] = tstudent(dot / (nrm1 * nrm2));   // numerator in fp32
    }
    __syncthreads();
    float sc1 = sc1_s, sc2 = sc2_s;
    unsigned short* d1 = n1 + (size_t)row * DIM;
    unsigned short* d2 = n2 + (size_t)row * DIM;
    d1[t]       = f2bf(a0 * sc1);
    d1[t + 256] = f2bf(a1 * sc1);
    d1[t + 512] = f2bf(a2 * sc1);
    d2[t]       = f2bf(b0 * sc2);
    d2[t + 256] = f2bf(b1 * sc2);
    d2[t + 512] = f2bf(b2 * sc2);
}

// ---------------- kernel 2: 256x256 8-wave bf16 GEMM, BK=32, 2 blocks/CU (TLP) ----------------
// LDS: [A buf0 16K][A buf1 16K][B buf0 16K][B buf1 16K] = 64 KiB -> 2 blocks/CU.
// Tile row = 32 bf16 = 64 B = 4 x 16B granules. Swizzle: granule g of row r stored
// at slot g ^ c(r), c(r) = ((r&3) + ((r>>2)&3)) & 3  -> quarter-wave reads are
// 2-way (free, m136); exact inverse applied on the global_load_lds SOURCE column
// (rule #21: linear LDS dest, pre-swizzled global src). No k-permutation at all.
// Schedule: 2 phases per K-tile, JIT fragment reads; stage all 4 ops for kt+1 at
// ph0(kt); one VMW(0)+BAR per tile (drain distance = full tile of MFMA >> L2
// latency; residual stall hidden by the co-resident block — m97/m114 TLP model).
// WAR-safe: MFMA's data dependency forces lgkm-completion of all ds_reads before
// the barrier; stage writes to a buffer only after the barrier that follows its
// last read.

__device__ __forceinline__ void stG(const unsigned short* g, char* lds, int t, int j) {
    __builtin_amdgcn_global_load_lds(
        (const __attribute__((address_space(1))) void*)(g + (size_t)j * 128 * DIM),
        (__attribute__((address_space(3))) void*)(lds + t * 16 + j * 8192), 16, 0, 0);
}

#define BAR()  asm volatile("s_barrier" ::: "memory")
#define VMW(n) asm volatile("s_waitcnt vmcnt(" #n ")" ::: "memory")

#define READ_B4()                                                               \
    bf16x8 bv[4];                                                               \
    _Pragma("unroll")                                                           \
    for (int n = 0; n < 4; ++n)                                                 \
        bv[n] = *(const bf16x8*)(Bb + rbB + n * 1024 + seg);

#define READ_A4(base_m)                                                         \
    bf16x8 av[4];                                                               \
    _Pragma("unroll")                                                           \
    for (int m = 0; m < 4; ++m)                                                 \
        av[m] = *(const bf16x8*)(Ab + rbA + ((base_m) + m) * 1024 + seg);

#define MFMA16(base_m)                                                          \
    __builtin_amdgcn_s_setprio(1);                                              \
    _Pragma("unroll")                                                           \
    for (int m = 0; m < 4; ++m)                                                 \
        _Pragma("unroll")                                                       \
        for (int n = 0; n < 4; ++n)                                             \
            acc[(base_m) + m][n] = __builtin_amdgcn_mfma_f32_16x16x32_bf16(     \
                av[m], bv[n], acc[(base_m) + m][n], 0, 0, 0);                   \
    __builtin_amdgcn_s_setprio(0);

__global__ __launch_bounds__(512, 4) void gemm_kernel(const unsigned short* __restrict__ n1,
                                                      const unsigned short* __restrict__ n2,
                                                      float* __restrict__ partial) {
    extern __shared__ char smem[];
    int t = threadIdx.x;
    int l = t & 63;
    int w = t >> 6;
    int wr = w >> 2;   // 0..1 -> A half (128 rows)
    int wc = w & 3;    // 0..3 -> B quarter (64 cols)

    // XCD-aware + L2 supertile mapping (1024 blocks, bijective)
    int bid = blockIdx.x;
    int xcd = bid & 7, idx = bid >> 3;
    int br = xcd * 4 + (idx & 3);
    int bc = (idx >> 4) * 4 + ((idx >> 2) & 3);
    int rowbase = br * BM, colbase = bc * BN;

    // staging: thread t covers LDS row sr = t>>2 (+128j), slot t&3.
    // slot s of row r holds granule s ^ c(r)  ->  fetch global granule (t&3) ^ c(sr).
    // c(r) invariant under +128j (128j = 0 mod 4 in both r&3 and (r>>2)&3 terms).
    int sr = t >> 2;
    int c_w = ((sr & 3) + ((sr >> 2) & 3)) & 3;
    int gcol0 = ((t & 3) ^ c_w) * 8;   // elements
    const unsigned short* Ag = n1 + (size_t)(rowbase + sr) * DIM + gcol0;
    const unsigned short* Bg = n2 + (size_t)(colbase + sr) * DIM + gcol0;

    f32x4 acc[8][4] = {};

    // read side: frag row r0 = l&15 (wr*128 / wc*64 offsets are 0 mod 4 in c(r)),
    // k-granule h = l>>4, slot = h ^ c(r0).
    int r0 = l & 15;
    int cr = ((r0 & 3) + ((r0 >> 2) & 3)) & 3;
    int seg = ((l >> 4) ^ cr) * 16;
    int rbA = (wr * 128 + r0) * 64;
    int rbB = (wc * 64 + r0) * 64;

    // prologue: stage K-tile 0 into buf0
    stG(Ag, smem, t, 0);         stG(Ag, smem, t, 1);
    stG(Bg, smem + 32768, t, 0); stG(Bg, smem + 32768, t, 1);
    VMW(0); BAR();

    for (int kt = 0; kt < KTILES - 1; ++kt) {
        int db = kt & 1;
        const char* Ab = smem + db * 16384;
        const char* Bb = smem + 32768 + db * 16384;
        char* AnW = smem + (db ^ 1) * 16384;
        char* BnW = smem + 32768 + (db ^ 1) * 16384;
        const unsigned short* Agn = Ag + (kt + 1) * BK;
        const unsigned short* Bgn = Bg + (kt + 1) * BK;

        // ph0: issue next-tile stage, compute m0-3
        stG(Agn, AnW, t, 0); stG(Agn, AnW, t, 1);
        stG(Bgn, BnW, t, 0); stG(Bgn, BnW, t, 1);
        READ_B4();
        { READ_A4(0); MFMA16(0); }
        // ph1: compute m4-7, then drain + publish
        { READ_A4(4); MFMA16(4); }
        VMW(0); BAR();
    }
    {   // peeled last tile (kt = 23, db = 1): no staging
        const char* Ab = smem + 16384;
        const char* Bb = smem + 32768 + 16384;
        READ_B4();
        { READ_A4(0); MFMA16(0); }
        { READ_A4(4); MFMA16(4); }
    }

    // ---------------- epilogue: t-Student + row sums ----------------
    // C/D map: row = wr*128 + m*16 + (l>>4)*4 + j (A-side), col = wc*64 + n*16 + (l&15)
    float* red = (float*)smem;  // 256 rows x 4 wc
    __syncthreads();            // all LDS reads of the K-loop done before reuse as 'red'
    #pragma unroll
    for (int m = 0; m < 8; ++m) {
        #pragma unroll
        for (int j = 0; j < 4; ++j) {
            float s = 0.f;
            #pragma unroll
            for (int n = 0; n < 4; ++n) s += tstudent(acc[m][n][j]);
            s += __shfl_xor(s, 1);
            s += __shfl_xor(s, 2);
            s += __shfl_xor(s, 4);
            s += __shfl_xor(s, 8);
            if ((l & 15) == 0) {
                int row = wr * 128 + m * 16 + (l >> 4) * 4 + j;
                red[row * 4 + wc] = s;
            }
        }
    }
    __syncthreads();
    if (t < BM) {
        partial[(size_t)bc * N_ROWS + rowbase + t] = red[t * 4 + 0] + red[t * 4 + 1] + red[t * 4 + 2] + red[t * 4 + 3];
    }
}

// ---------------- kernel 3: per-row denom + ratio, per-block sums ----------------
__global__ __launch_bounds__(256) void reduce_kernel(const float* __restrict__ partial,
                                                     const float* __restrict__ num,
                                                     float* __restrict__ blocksum) {
    int row = blockIdx.x * 256 + threadIdx.x;
    float d = 0.f;
    #pragma unroll 8
    for (int ct = 0; ct < NT2; ++ct) d += partial[(size_t)ct * N_ROWS + row];
    float s = num[row] / d;
    for (int off = 32; off; off >>= 1) s += __shfl_down(s, off);
    __shared__ float wsum[4];
    if ((threadIdx.x & 63) == 0) wsum[threadIdx.x >> 6] = s;
    __syncthreads();
    if (threadIdx.x == 0) blocksum[blockIdx.x] = wsum[0] + wsum[1] + wsum[2] + wsum[3];
}

// ---------------- kernel 4: final scalar ----------------
__global__ __launch_bounds__(64) void final_kernel(const float* __restrict__ blocksum,
                                                   float* __restrict__ out) {
    int l = threadIdx.x;
    float s = (l < 32) ? blocksum[l] : 0.f;
    for (int off = 32; off; off >>= 1) s += __shfl_down(s, off);
    if (l == 0) out[0] = -(s / (float)N_ROWS);
}

extern "C" void kernel_launch(void* const* d_in, const int* in_sizes, int n_in,
                              void* d_out, int out_size, void* d_ws, size_t ws_size,
                              hipStream_t stream) {
    const float* z1 = (const float*)d_in[0];
    const float* z2 = (const float*)d_in[1];
    char* ws = (char*)d_ws;
    const size_t n_bytes = (size_t)N_ROWS * DIM * 2;  // 12,582,912 (bf16)
    unsigned short* n1 = (unsigned short*)ws;
    unsigned short* n2 = (unsigned short*)(ws + n_bytes);
    float* num      = (float*)(ws + 2 * n_bytes);                     // 32 KB
    float* partial  = (float*)(ws + 2 * n_bytes + 32768);             // 1 MB used
    float* blocksum = (float*)(ws + 2 * n_bytes + 32768 + 2097152);   // 128 B

    hipFuncSetAttribute((const void*)gemm_kernel,
                        hipFuncAttributeMaxDynamicSharedMemorySize, LDS_BYTES);

    norm_kernel<<<N_ROWS, 256, 0, stream>>>(z1, z2, n1, n2, num);
    gemm_kernel<<<NT2 * NT2, 512, LDS_BYTES, stream>>>(n1, n2, partial);
    reduce_kernel<<<N_ROWS / 256, 256, 0, stream>>>(partial, num, blocksum);
    final_kernel<<<1, 64, 0, stream>>>(blocksum, (float*)d_out);
}

// Round 9
// 95.297 us; speedup vs baseline: 7.3296x; 7.3296x over previous
//
#include <hip/hip_runtime.h>
#include <hip/hip_bf16.h>
#include <stdint.h>

#define N_ROWS 8192
#define DIM    768          // elements per row; == BYTES per row in int8
#define BM     256
#define BN     256
#define BKB    128          // K-tile bytes (= i8 elements)
#define KTILES (DIM / BKB)  // 6
#define NT2    (N_ROWS / BN)
#define LDS_BYTES 131072

typedef __attribute__((ext_vector_type(4))) int   i32x4;
typedef __attribute__((ext_vector_type(4))) float f32x4;

__device__ __forceinline__ float tstudent(float c) {
    // (1 + 0.5*(1-c))^{-1.5} = t^{-1.5}, t = 1.5 - 0.5c
    float t = 1.5f - 0.5f * c;
    float r = rsqrtf(t);
    return r * r * r;
}

// ---------------- kernel 1: row L2-normalize fp32 -> int8, fp32 diag numerator, post-quant inv-norms ----------------
__global__ __launch_bounds__(256) void norm_kernel(const float* __restrict__ z1,
                                                   const float* __restrict__ z2,
                                                   signed char* __restrict__ n1,
                                                   signed char* __restrict__ n2,
                                                   float* __restrict__ num,
                                                   float* __restrict__ inva,
                                                   float* __restrict__ invb) {
    int row = blockIdx.x;
    int t = threadIdx.x;
    const float* s1 = z1 + (size_t)row * DIM;
    const float* s2 = z2 + (size_t)row * DIM;
    float a0 = s1[t], a1 = s1[t + 256], a2 = s1[t + 512];
    float b0 = s2[t], b1 = s2[t + 256], b2 = s2[t + 512];
    float ss1 = a0 * a0 + a1 * a1 + a2 * a2;
    float ss2 = b0 * b0 + b1 * b1 + b2 * b2;
    float sd  = a0 * b0 + a1 * b1 + a2 * b2;
    for (int off = 32; off; off >>= 1) {
        ss1 += __shfl_down(ss1, off);
        ss2 += __shfl_down(ss2, off);
        sd  += __shfl_down(sd, off);
    }
    __shared__ float w1[4], w2[4], wd[4];
    __shared__ float sc1_s, sc2_s;
    if ((t & 63) == 0) { int wi = t >> 6; w1[wi] = ss1; w2[wi] = ss2; wd[wi] = sd; }
    __syncthreads();
    if (t == 0) {
        float nrm1 = fmaxf(sqrtf(w1[0] + w1[1] + w1[2] + w1[3]), 1e-8f);
        float nrm2 = fmaxf(sqrtf(w2[0] + w2[1] + w2[2] + w2[3]), 1e-8f);
        float dot  = wd[0] + wd[1] + wd[2] + wd[3];
        sc1_s = 127.0f / nrm1;
        sc2_s = 127.0f / nrm2;
        num[row] = tstudent(dot / (nrm1 * nrm2));   // numerator exact in fp32
    }
    __syncthreads();
    float sc1 = sc1_s, sc2 = sc2_s;
    // quantize: q = clamp(round(127 * x_hat))
    float qa0 = fminf(fmaxf(rintf(a0 * sc1), -127.f), 127.f);
    float qa1 = fminf(fmaxf(rintf(a1 * sc1), -127.f), 127.f);
    float qa2 = fminf(fmaxf(rintf(a2 * sc1), -127.f), 127.f);
    float qb0 = fminf(fmaxf(rintf(b0 * sc2), -127.f), 127.f);
    float qb1 = fminf(fmaxf(rintf(b1 * sc2), -127.f), 127.f);
    float qb2 = fminf(fmaxf(rintf(b2 * sc2), -127.f), 127.f);
    signed char* d1 = n1 + (size_t)row * DIM;
    signed char* d2 = n2 + (size_t)row * DIM;
    d1[t]       = (signed char)(int)qa0;
    d1[t + 256] = (signed char)(int)qa1;
    d1[t + 512] = (signed char)(int)qa2;
    d2[t]       = (signed char)(int)qb0;
    d2[t + 256] = (signed char)(int)qb1;
    d2[t + 512] = (signed char)(int)qb2;
    // post-quantization inverse norms (exact correction factors for cos)
    float sq1 = qa0 * qa0 + qa1 * qa1 + qa2 * qa2;   // integer-valued, exact in fp32
    float sq2 = qb0 * qb0 + qb1 * qb1 + qb2 * qb2;
    for (int off = 32; off; off >>= 1) {
        sq1 += __shfl_down(sq1, off);
        sq2 += __shfl_down(sq2, off);
    }
    __shared__ float wq1[4], wq2[4];
    if ((t & 63) == 0) { int wi = t >> 6; wq1[wi] = sq1; wq2[wi] = sq2; }
    __syncthreads();
    if (t == 0) {
        inva[row] = rsqrtf(wq1[0] + wq1[1] + wq1[2] + wq1[3]);
        invb[row] = rsqrtf(wq2[0] + wq2[1] + wq2[2] + wq2[3]);
    }
}

// ---------------- kernel 2: 256x256 8-wave int8 MFMA GEMM (K=64/instr), R5 schedule ----------------
// LDS: [A buf0 32K][A buf1 32K][B buf0 32K][B buf1 32K] = 128 KiB (identical to R5 bf16:
// row = 128 B, swizzle slot = granule ^ (row & 7), linear LDS dest + inverse-swizzled
// global source column for global_load_lds).
// MFMA: mfma_i32_16x16x64_i8 — 4-VGPR A/B frags (16 i8 at k = 16*(l>>4) + ks*64),
// 4-reg i32 acc. Same instruction count/rate per K-tile as R5's bf16, but 2x K-work
// -> 6 K-tiles instead of 12. Register shape identical to R5 (no i32x8 tuples).
// Schedule/ledger verbatim R5: stage B0,B1|B2,B3|A0,A2|A1,A3 (2/phase);
// VMW(4)@ph1 drains late-A(kt); VMW(2)@ph3 drains B+early-A(kt+1); invariant
// [A1,A3] in flight; read-ahead one phase (aS0/aS1 ping-pong, B-seg0 across tiles).

__device__ __forceinline__ void stG(const signed char* g, char* lds, int t, int j) {
    __builtin_amdgcn_global_load_lds(
        (const __attribute__((address_space(1))) void*)(g + (size_t)j * 64 * DIM),
        (__attribute__((address_space(3))) void*)(lds + t * 16 + j * 8192), 16, 0, 0);
}

#define BAR()  asm volatile("s_barrier" ::: "memory")
#define VMW(n) asm volatile("s_waitcnt vmcnt(" #n ")" ::: "memory")

#define READ_AQ(set, Abase, q)                                                  \
    set[0] = *(const i32x4*)((Abase) + rbA + ((q)*2    ) * 2048 + seg0);        \
    set[1] = *(const i32x4*)((Abase) + rbA + ((q)*2    ) * 2048 + seg1);        \
    set[2] = *(const i32x4*)((Abase) + rbA + ((q)*2 + 1) * 2048 + seg0);        \
    set[3] = *(const i32x4*)((Abase) + rbA + ((q)*2 + 1) * 2048 + seg1);

#define READ_BSEG0(dst, Bbase)                                                  \
    dst[0] = *(const i32x4*)((Bbase) + rbB + 0 * 2048 + seg0);                  \
    dst[1] = *(const i32x4*)((Bbase) + rbB + 1 * 2048 + seg0);                  \
    dst[2] = *(const i32x4*)((Bbase) + rbB + 2 * 2048 + seg0);                  \
    dst[3] = *(const i32x4*)((Bbase) + rbB + 3 * 2048 + seg0);

#define READ_BSEG1(Bbase)                                                       \
    bSeg1[0] = *(const i32x4*)((Bbase) + rbB + 0 * 2048 + seg1);                \
    bSeg1[1] = *(const i32x4*)((Bbase) + rbB + 1 * 2048 + seg1);                \
    bSeg1[2] = *(const i32x4*)((Bbase) + rbB + 2 * 2048 + seg1);                \
    bSeg1[3] = *(const i32x4*)((Bbase) + rbB + 3 * 2048 + seg1);

// seg0 (k-step 0) pairs with BS0; seg1 (k-step 1) pairs with bSeg1.
#define MFMA_Q(q, AS, BS0)                                                                                  \
    __builtin_amdgcn_s_setprio(1);                                                                          \
    _Pragma("unroll")                                                                                       \
    for (int n = 0; n < 4; ++n) {                                                                           \
        acc[(q)*2][n]     = __builtin_amdgcn_mfma_i32_16x16x64_i8(AS[0], BS0[n], acc[(q)*2][n], 0, 0, 0);       \
        acc[(q)*2][n]     = __builtin_amdgcn_mfma_i32_16x16x64_i8(AS[1], bSeg1[n], acc[(q)*2][n], 0, 0, 0);     \
        acc[(q)*2 + 1][n] = __builtin_amdgcn_mfma_i32_16x16x64_i8(AS[2], BS0[n], acc[(q)*2 + 1][n], 0, 0, 0);   \
        acc[(q)*2 + 1][n] = __builtin_amdgcn_mfma_i32_16x16x64_i8(AS[3], bSeg1[n], acc[(q)*2 + 1][n], 0, 0, 0); \
    }                                                                                                       \
    __builtin_amdgcn_s_setprio(0);

#define TILE(kt, B0c, B0n, PAR)                                                 \
    {                                                                           \
        const char* Ab  = smem + (PAR) * 32768;                                 \
        const char* Bb  = smem + 65536 + (PAR) * 32768;                         \
        const char* AbN = smem + ((PAR) ^ 1) * 32768;                           \
        const char* BbN = smem + 65536 + ((PAR) ^ 1) * 32768;                   \
        char* AnW = smem + ((PAR) ^ 1) * 32768;                                 \
        char* BnW = smem + 65536 + ((PAR) ^ 1) * 32768;                         \
        const signed char* Agn = Ag + ((kt) + 1) * BKB;                         \
        const signed char* Bgn = Bg + ((kt) + 1) * BKB;                         \
        /* ph0 */                                                               \
        stG(Bgn, BnW, t, 0); stG(Bgn, BnW, t, 1);                               \
        READ_BSEG1(Bb);                                                         \
        READ_AQ(aS1, Ab, 1);                                                    \
        MFMA_Q(0, aS0, B0c);                                                    \
        /* ph1 */                                                               \
        stG(Bgn, BnW, t, 2); stG(Bgn, BnW, t, 3);                               \
        VMW(4); BAR();                                                          \
        READ_AQ(aS0, Ab, 2);                                                    \
        MFMA_Q(1, aS1, B0c);                                                    \
        /* ph2 */                                                               \
        stG(Agn, AnW, t, 0); stG(Agn, AnW, t, 2);                               \
        READ_AQ(aS1, Ab, 3);                                                    \
        MFMA_Q(2, aS0, B0c);                                                    \
        /* ph3 */                                                               \
        stG(Agn, AnW, t, 1); stG(Agn, AnW, t, 3);                               \
        VMW(2); BAR();                                                          \
        READ_BSEG0(B0n, BbN);                                                   \
        READ_AQ(aS0, AbN, 0);                                                   \
        MFMA_Q(3, aS1, B0c);                                                    \
    }

__global__ __launch_bounds__(512, 2) void gemm_kernel(const signed char* __restrict__ n1,
                                                      const signed char* __restrict__ n2,
                                                      const float* __restrict__ inva,
                                                      const float* __restrict__ invb,
                                                      float* __restrict__ partial) {
    extern __shared__ char smem[];
    int t = threadIdx.x;
    int l = t & 63;
    int w = t >> 6;
    int wr = w >> 2;   // 0..1 -> A half (128 rows)
    int wc = w & 3;    // 0..3 -> B quarter (64 cols)

    // XCD-aware + L2 supertile mapping (1024 blocks, bijective)
    int bid = blockIdx.x;
    int xcd = bid & 7, idx = bid >> 3;
    int br = xcd * 4 + (idx & 3);
    int bc = (idx >> 4) * 4 + ((idx >> 2) & 3);
    int rowbase = br * BM, colbase = bc * BN;

    // staging: thread t covers LDS rows (t>>3)+64j, granule t&7;
    // inverse-swizzled global 16B-granule = (t&7) ^ ((t>>3)&7)
    int sr = t >> 3;
    int gcol0 = ((t & 7) ^ (sr & 7)) * 16;
    const signed char* Ag = n1 + (size_t)(rowbase + sr) * DIM + gcol0;
    const signed char* Bg = n2 + (size_t)(colbase + sr) * DIM + gcol0;

    i32x4 acc[8][4] = {};

    // read side: frag row r = l&15, true granule h = (l>>4) + 4*ks, slot = h ^ (r&7)
    int seg0 = (((l >> 4) + 0) ^ (l & 7)) * 16;
    int seg1 = (((l >> 4) + 4) ^ (l & 7)) * 16;
    int rbA = (wr * 128 + (l & 15)) * 128;
    int rbB = (wc * 64 + (l & 15)) * 128;

    i32x4 aS0[4], aS1[4];
    i32x4 bB0s0[4], bB1s0[4];
    i32x4 bSeg1[4];

    // prologue: stage K-tile 0 into buf0 (B0..B3, A0, A2, A1, A3)
    {
        char* A0b = smem;
        char* B0b = smem + 65536;
        stG(Bg, B0b, t, 0); stG(Bg, B0b, t, 1); stG(Bg, B0b, t, 2); stG(Bg, B0b, t, 3);
        stG(Ag, A0b, t, 0); stG(Ag, A0b, t, 2); stG(Ag, A0b, t, 1); stG(Ag, A0b, t, 3);
    }
    VMW(2);   // drains B0-3, A0, A2; leaves [A1,A3] in flight (pipeline invariant)
    BAR();
    READ_BSEG0(bB0s0, smem + 65536);
    READ_AQ(aS0, smem, 0);

    TILE(0, bB0s0, bB1s0, 0)
    TILE(1, bB1s0, bB0s0, 1)
    TILE(2, bB0s0, bB1s0, 0)
    TILE(3, bB1s0, bB0s0, 1)
    TILE(4, bB0s0, bB1s0, 0)
    {   // peeled tile 5 (parity 1, B-seg0 prefetched in bB1s0; no staging)
        const char* Ab = smem + 32768;
        const char* Bb = smem + 65536 + 32768;
        /* ph0 */
        READ_BSEG1(Bb);
        READ_AQ(aS1, Ab, 1);
        MFMA_Q(0, aS0, bB1s0);
        /* ph1 — drain late-A of this tile before q2 reads */
        VMW(0); BAR();
        READ_AQ(aS0, Ab, 2);
        MFMA_Q(1, aS1, bB1s0);
        /* ph2 */
        READ_AQ(aS1, Ab, 3);
        MFMA_Q(2, aS0, bB1s0);
        /* ph3 */
        MFMA_Q(3, aS1, bB1s0);
    }

    // ---------------- epilogue: cos = acc * inva[row] * invb[col]; t-Student + row sums ----------------
    // C/D map: row = wr*128 + m*16 + (l>>4)*4 + j (A-side), col = wc*64 + n*16 + (l&15)
    float invb_n[4];
    #pragma unroll
    for (int n = 0; n < 4; ++n)
        invb_n[n] = invb[colbase + wc * 64 + n * 16 + (l & 15)];

    float* red = (float*)smem;
    __syncthreads();
    #pragma unroll
    for (int m = 0; m < 8; ++m) {
        f32x4 ia = *(const f32x4*)(inva + rowbase + wr * 128 + m * 16 + (l >> 4) * 4);
        #pragma unroll
        for (int j = 0; j < 4; ++j) {
            float s = 0.f;
            #pragma unroll
            for (int n = 0; n < 4; ++n) {
                float cos = (float)acc[m][n][j] * ia[j] * invb_n[n];
                s += tstudent(cos);
            }
            s += __shfl_xor(s, 1);
            s += __shfl_xor(s, 2);
            s += __shfl_xor(s, 4);
            s += __shfl_xor(s, 8);
            if ((l & 15) == 0) {
                int row = wr * 128 + m * 16 + (l >> 4) * 4 + j;
                red[row * 4 + wc] = s;
            }
        }
    }
    __syncthreads();
    if (t < BM) {
        partial[(size_t)bc * N_ROWS + rowbase + t] = red[t * 4 + 0] + red[t * 4 + 1] + red[t * 4 + 2] + red[t * 4 + 3];
    }
}

// ---------------- kernel 3: per-row denom + ratio, per-block sums ----------------
__global__ __launch_bounds__(256) void reduce_kernel(const float* __restrict__ partial,
                                                     const float* __restrict__ num,
                                                     float* __restrict__ blocksum) {
    int row = blockIdx.x * 256 + threadIdx.x;
    float d = 0.f;
    #pragma unroll 8
    for (int ct = 0; ct < NT2; ++ct) d += partial[(size_t)ct * N_ROWS + row];
    float s = num[row] / d;
    for (int off = 32; off; off >>= 1) s += __shfl_down(s, off);
    __shared__ float wsum[4];
    if ((threadIdx.x & 63) == 0) wsum[threadIdx.x >> 6] = s;
    __syncthreads();
    if (threadIdx.x == 0) blocksum[blockIdx.x] = wsum[0] + wsum[1] + wsum[2] + wsum[3];
}

// ---------------- kernel 4: final scalar ----------------
__global__ __launch_bounds__(64) void final_kernel(const float* __restrict__ blocksum,
                                                   float* __restrict__ out) {
    int l = threadIdx.x;
    float s = (l < 32) ? blocksum[l] : 0.f;
    for (int off = 32; off; off >>= 1) s += __shfl_down(s, off);
    if (l == 0) out[0] = -(s / (float)N_ROWS);
}

extern "C" void kernel_launch(void* const* d_in, const int* in_sizes, int n_in,
                              void* d_out, int out_size, void* d_ws, size_t ws_size,
                              hipStream_t stream) {
    const float* z1 = (const float*)d_in[0];
    const float* z2 = (const float*)d_in[1];
    char* ws = (char*)d_ws;
    const size_t n_bytes = (size_t)N_ROWS * DIM;   // 6,291,456 (int8)
    signed char* n1 = (signed char*)ws;
    signed char* n2 = (signed char*)(ws + n_bytes);
    size_t base2 = 2 * n_bytes;
    float* num      = (float*)(ws + base2);                    // 32 KB
    float* inva     = (float*)(ws + base2 + 32768);            // 32 KB
    float* invb     = (float*)(ws + base2 + 65536);            // 32 KB
    float* partial  = (float*)(ws + base2 + 98304);            // 1 MB used
    float* blocksum = (float*)(ws + base2 + 98304 + 2097152);  // 128 B

    hipFuncSetAttribute((const void*)gemm_kernel,
                        hipFuncAttributeMaxDynamicSharedMemorySize, LDS_BYTES);

    norm_kernel<<<N_ROWS, 256, 0, stream>>>(z1, z2, n1, n2, num, inva, invb);
    gemm_kernel<<<NT2 * NT2, 512, LDS_BYTES, stream>>>(n1, n2, inva, invb, partial);
    reduce_kernel<<<N_ROWS / 256, 256, 0, stream>>>(partial, num, blocksum);
    final_kernel<<<1, 64, 0, stream>>>(blocksum, (float*)d_out);
}